// Round 4
// baseline (504.478 us; speedup 1.0000x reference)
//
#include <hip/hip_runtime.h>
#include <hip/hip_bf16.h>

typedef __attribute__((ext_vector_type(4))) float f32x4;
typedef __attribute__((ext_vector_type(8))) short s16x8;

static __device__ __forceinline__ short f2bf(float x) {
  __hip_bfloat16 h = __float2bfloat16(x);
  return *reinterpret_cast<short*>(&h);
}

// Intra-wave LDS fence: wait for own wave's DS ops; sched_barrier stops hipcc
// from hoisting anything across it (guide rule #18).
static __device__ __forceinline__ void wave_lgkm0() {
  asm volatile("s_waitcnt lgkmcnt(0)" ::: "memory");
  __builtin_amdgcn_sched_barrier(0);
}

// ---------------- software grid barrier (capture-safe, self-resetting; proven r3) ----------------
__device__ __align__(128) unsigned g_cnt;
__device__ __align__(128) unsigned g_gen;

static __device__ __forceinline__ void gridbar(unsigned nb) {
  __syncthreads();
  if (threadIdx.x == 0) {
    __threadfence();
    unsigned gen = __hip_atomic_load(&g_gen, __ATOMIC_RELAXED, __HIP_MEMORY_SCOPE_AGENT);
    unsigned arrived = __hip_atomic_fetch_add(&g_cnt, 1u, __ATOMIC_ACQ_REL,
                                              __HIP_MEMORY_SCOPE_AGENT) + 1u;
    if (arrived == nb) {
      __hip_atomic_store(&g_cnt, 0u, __ATOMIC_RELAXED, __HIP_MEMORY_SCOPE_AGENT);
      __hip_atomic_store(&g_gen, gen + 1u, __ATOMIC_RELEASE, __HIP_MEMORY_SCOPE_AGENT);
    } else {
      while (__hip_atomic_load(&g_gen, __ATOMIC_ACQUIRE, __HIP_MEMORY_SCOPE_AGENT) == gen)
        __builtin_amdgcn_s_sleep(2);
    }
    __threadfence();
  }
  __syncthreads();
}

// -------- shared memory (58.2 KB static; 256 blocks co-resident trivially) --------
struct Smem {
  float u4[20][64][4];       // [site][b][g] f32
  float vls[64][36];         // A-layout v copy; cols 20..35 stay zero
  float Lw[400];             // per-stage label*omega projection
  short CS[4][20][168];      // C' chunk: [site][n-row 0..20][k' 0..160 +pad]
  float redA[4], redB[4], stats[2];
};
struct F4Smem {              // overlays Smem in the final phase
  float ybuf[4][160];        // per-wave y rows for current chunk
  float M[4][400];           // per-wave site transfer matrix
  float Pb[4][2][400];       // per-wave running product (ping-pong)
  float chunkP[8][400];      // the 8 chunk products of this b
  float TA[2][400];          // combine ping-pong
  float LwF[200];
  float va[20];
};

// ---------------- MPS stage: bulk C' build + barrier-free wave-autonomous chain ----------------
// Wave q owns batch rows [16q,16q+16). v persists in REGISTERS in MFMA D-layout
// (lane (m,quad) holds rows quad*4+r, cols m and m+16); acc is initialized with v
// so MFMA's C-operand does the v+dv add. vls is only the D->A relayout buffer
// (intra-wave, lgkmcnt-ordered, no block barrier in the site loop).
// CS rows >=20-k'-columns were zeroed once at kernel start and are never written,
// so A(=0 there) x B(=0) cannot produce NaN; acc1 cols for m>=4 read a clamped
// valid row (finite, discarded).
template<int STAGE>
static __device__ void mps_stage(Smem& sm, int p, int t,
    const float* __restrict__ xsrc, const float* __restrict__ ysrc,
    const float* __restrict__ cores, const float* __restrict__ alpha,
    const float* __restrict__ gam, const float* __restrict__ bet,
    float* __restrict__ yout) {
  constexpr int S = (STAGE == 1) ? 3 : 20;
  constexpr int CH = 4;
  const int b = t & 63, q = t >> 6;
  const int m = b & 15, quad = b >> 4;
  const int bl = q * 16 + m;
  const int mrow1 = (m < 4) ? m + 16 : m;   // clamped C' row for acc1 (junk cols discarded)

  // ---- init v (LDS A-copy + register D-copy) ----
  for (int i = t; i < 64 * 36; i += 256) {
    int col = i % 36;
    sm.vls[i / 36][col] = (col < 20) ? alpha[col] : 0.f;
  }
  float vreg0[4], vreg1[4];
  {
    float a0 = alpha[m];
    float a1 = (m < 4) ? alpha[m + 16] : 0.f;
#pragma unroll
    for (int r = 0; r < 4; ++r) { vreg0[r] = a0; vreg1[r] = a1; }
  }

  // ---- gather u (faithful raw-reshape unfold permutation; verbatim) ----
  for (int k = 0; k < S; ++k) {
    float val;
    if (STAGE == 1) {
      int L = q * 3072 + p * 3 + k;           // [4,1024,3] flat
      int c = L >> 12, r = L & 4095;          // dims [3,32,32,2,2]
      int hh = 2 * (r >> 7) + ((r >> 1) & 1);
      int ww = 2 * ((r >> 2) & 31) + (r & 1);
      val = xsrc[(b * 3 + c) * 4096 + hh * 64 + ww];
    } else if (STAGE == 2) {
      int L = q * 5120 + p * 20 + k;          // [4,256,20] flat
      int c = L >> 10, r = L & 1023;          // dims [20,16,16,2,2]
      int f = c * 1024 + (2 * (r >> 6) + ((r >> 1) & 1)) * 32
                        + (2 * ((r >> 2) & 15) + (r & 1));
      val = ysrc[f * 64 + b];
    } else {
      int L = q * 1280 + p * 20 + k;          // [4,64,20] flat
      int c = L >> 8, r = L & 255;            // dims [20,8,8,2,2]
      int f = c * 256 + (2 * (r >> 5) + ((r >> 1) & 1)) * 16
                       + (2 * ((r >> 2) & 7) + (r & 1));
      val = ysrc[f * 64 + b];
    }
    sm.u4[k][b][q] = val;
  }

  const float* cbase = cores + (size_t)p * S * 3200;

  // ---- chunked: cooperative bulk C' build, then barrier-free chain ----
  for (int c0 = 0; c0 < S; c0 += CH) {
    const int ns = (S - c0 < CH) ? (S - c0) : CH;
    __syncthreads();                       // CS reuse fence (+ init/gather fence on 1st)
    for (int uidx = t; uidx < ns * 400; uidx += 256) {
      const int ls = uidx / 400, e = uidx - ls * 400;
      const float* cs = cbase + (size_t)(c0 + ls) * 3200;
      float r0 = cs[e],        r1 = cs[400 + e],  r2 = cs[800 + e],  r3 = cs[1200 + e];
      float r4 = cs[1600 + e], r5 = cs[2000 + e], r6 = cs[2400 + e], r7 = cs[2800 + e];
      const int i = e / 20, j = e - i * 20;
      short* row = &sm.CS[ls][j][0];
      row[i]       = f2bf(r0 - r4);
      row[32 + i]  = f2bf(r1 - r5);
      row[64 + i]  = f2bf(r2 - r6);
      row[96 + i]  = f2bf(r3 - r7);
      float csum = r4 + r5 + r6 + r7;
      if (i == j) csum -= 1.f;
      row[128 + i] = f2bf(csum);
    }
    __syncthreads();
    for (int ls = 0; ls < ns; ++ls) {
      const int s = c0 + ls;
      const float4 uu4 = *(const float4*)&sm.u4[s][bl][0];
      const float4 va4 = *(const float4*)&sm.vls[bl][quad * 8];
      const float4 vb4 = *(const float4*)&sm.vls[bl][quad * 8 + 4];
      const float vv[8] = {va4.x, va4.y, va4.z, va4.w, vb4.x, vb4.y, vb4.z, vb4.w};
      const float um[5] = {uu4.x, uu4.y, uu4.z, uu4.w, 1.f};
      f32x4 acc0, acc1;
#pragma unroll
      for (int r = 0; r < 4; ++r) { acc0[r] = vreg0[r]; acc1[r] = vreg1[r]; }
#pragma unroll
      for (int kt = 0; kt < 5; ++kt) {
        s16x8 aF;
#pragma unroll
        for (int j2 = 0; j2 < 8; ++j2) aF[j2] = f2bf(vv[j2] * um[kt]);
        const s16x8 bF0 = *(const s16x8*)&sm.CS[ls][m][kt * 32 + quad * 8];
        const s16x8 bF1 = *(const s16x8*)&sm.CS[ls][mrow1][kt * 32 + quad * 8];
        acc0 = __builtin_amdgcn_mfma_f32_16x16x32_bf16(aF, bF0, acc0, 0, 0, 0);
        acc1 = __builtin_amdgcn_mfma_f32_16x16x32_bf16(aF, bF1, acc1, 0, 0, 0);
      }
#pragma unroll
      for (int r = 0; r < 4; ++r) { vreg0[r] = acc0[r]; vreg1[r] = acc1[r]; }
      // publish D->A relayout for next site (intra-wave only)
#pragma unroll
      for (int r = 0; r < 4; ++r) sm.vls[q * 16 + quad * 4 + r][m] = acc0[r];
      if (m < 4) {
#pragma unroll
        for (int r = 0; r < 4; ++r) sm.vls[q * 16 + quad * 4 + r][m + 16] = acc1[r];
      }
      wave_lgkm0();
    }
  }
  __syncthreads();

  // ---- epilogue: Lw projection + fused BatchNorm (verbatim) ----
  float vf[20];
  {
    const float4 v0 = *(const float4*)&sm.vls[b][0];
    const float4 v1 = *(const float4*)&sm.vls[b][4];
    const float4 v2 = *(const float4*)&sm.vls[b][8];
    const float4 v3 = *(const float4*)&sm.vls[b][12];
    const float4 v4 = *(const float4*)&sm.vls[b][16];
    vf[0]=v0.x; vf[1]=v0.y; vf[2]=v0.z; vf[3]=v0.w;
    vf[4]=v1.x; vf[5]=v1.y; vf[6]=v1.z; vf[7]=v1.w;
    vf[8]=v2.x; vf[9]=v2.y; vf[10]=v2.z; vf[11]=v2.w;
    vf[12]=v3.x; vf[13]=v3.y; vf[14]=v3.z; vf[15]=v3.w;
    vf[16]=v4.x; vf[17]=v4.y; vf[18]=v4.z; vf[19]=v4.w;
  }
  float yo[5];
  float s1 = 0.f, s2 = 0.f;
#pragma unroll
  for (int jj = 0; jj < 5; ++jj) {
    int o = q * 5 + jj;
    float a = 0.f;
#pragma unroll
    for (int j = 0; j < 20; ++j) a = fmaf(vf[j], sm.Lw[o * 20 + j], a);
    yo[jj] = a; s1 += a; s2 += a * a;
  }
#pragma unroll
  for (int off = 32; off > 0; off >>= 1) {
    s1 += __shfl_down(s1, off); s2 += __shfl_down(s2, off);
  }
  if (b == 0) { sm.redA[q] = s1; sm.redB[q] = s2; }
  __syncthreads();
  if (t == 0) {
    float S1 = sm.redA[0] + sm.redA[1] + sm.redA[2] + sm.redA[3];
    float S2 = sm.redB[0] + sm.redB[1] + sm.redB[2] + sm.redB[3];
    float mu = S1 * (1.f / 1280.f);
    float var = S2 * (1.f / 1280.f) - mu * mu;
    if (var < 0.f) var = 0.f;
    sm.stats[0] = mu; sm.stats[1] = var;
  }
  __syncthreads();
  float mu = sm.stats[0], var = sm.stats[1];
  float scale = gam[p] / sqrtf(var + 1e-5f);
  float shift = bet[p] - mu * scale;
#pragma unroll
  for (int jj = 0; jj < 5; ++jj) {
    int o = q * 5 + jj;
    yout[(p * 20 + o) * 64 + b] = fmaf(yo[jj], scale, shift);
  }
}

// ---------------- final MPS: wave-autonomous chunk products + sequential combine ----------------
// Block bb (<64): 8 chunks c, 2 per wave. Math/association is bit-identical to the
// proven k_f1 (sequential 8-site product per chunk) and k_f2 (sequential combine).
static __device__ void final_mps(F4Smem& sf, int bb, int t,
                                 const float* __restrict__ y3n,
                                 const float* __restrict__ coresF,
                                 const float* __restrict__ alphaF,
                                 const float* __restrict__ labelF,
                                 const float* __restrict__ omegaF,
                                 float* __restrict__ out) {
  const int lane = t & 63, q = t >> 6;
  if (t < 200) {
    int o = t / 20, j = t % 20;
    float a = 0.f;
#pragma unroll
    for (int k = 0; k < 20; ++k) a = fmaf(labelF[o * 400 + j * 20 + k], omegaF[k], a);
    sf.LwF[t] = a;
  }
  for (int pass = 0; pass < 2; ++pass) {
    const int c = q * 2 + pass;
    float* yb = sf.ybuf[q];
    float* M  = sf.M[q];
    auto&  Pb = sf.Pb[q];
    for (int idx = lane; idx < 160; idx += 64)
      yb[idx] = y3n[(c * 160 + idx) * 64 + bb];
    wave_lgkm0();
    int cur = 0;
    for (int s = 0; s < 8; ++s) {
      const float* cf = coresF + (size_t)(c * 8 + s) * 16000;
      for (int e = lane; e < 400; e += 64) {
        float a = 0.f;
#pragma unroll
        for (int g = 0; g < 20; ++g) {
          float lo = cf[g * 400 + e], hi = cf[(g + 20) * 400 + e];
          a += fmaf(yb[s * 20 + g], lo - hi, hi);
        }
        M[e] = a;
      }
      wave_lgkm0();
      if (s == 0) {
        for (int e = lane; e < 400; e += 64) Pb[0][e] = M[e];
      } else {
        for (int e = lane; e < 400; e += 64) {
          int i = e / 20, j = e - i * 20;
          float a = 0.f;
#pragma unroll
          for (int k = 0; k < 20; ++k) a = fmaf(Pb[cur][i * 20 + k], M[k * 20 + j], a);
          Pb[cur ^ 1][e] = a;
        }
        cur ^= 1;
      }
      wave_lgkm0();
    }
    for (int e = lane; e < 400; e += 64) sf.chunkP[c][e] = Pb[cur][e];
    wave_lgkm0();
  }
  __syncthreads();
  // sequential combine R = ((P0*P1)*P2)*... (matches proven k_f2 association)
  for (int e = t; e < 400; e += 256) sf.TA[0][e] = sf.chunkP[0][e];
  __syncthreads();
  int cur = 0;
  for (int c = 1; c < 8; ++c) {
    for (int e = t; e < 400; e += 256) {
      int i = e / 20, j = e - i * 20;
      float a = 0.f;
#pragma unroll
      for (int k = 0; k < 20; ++k) a = fmaf(sf.TA[cur][i * 20 + k], sf.chunkP[c][k * 20 + j], a);
      sf.TA[cur ^ 1][e] = a;
    }
    cur ^= 1;
    __syncthreads();
  }
  if (t < 20) {
    float a = 0.f;
#pragma unroll
    for (int i = 0; i < 20; ++i) a = fmaf(alphaF[i], sf.TA[cur][i * 20 + t], a);
    sf.va[t] = a;
  }
  __syncthreads();
  if (t < 10) {
    float a = 0.f;
#pragma unroll
    for (int j = 0; j < 20; ++j) a = fmaf(sf.va[j], sf.LwF[t * 20 + j], a);
    out[bb * 10 + t] = a;
  }
}

// ---------------- the single fused kernel ----------------
__global__ __launch_bounds__(256, 1)
void k_all(const float* __restrict__ x,
           const float* __restrict__ cores1, const float* __restrict__ label1,
           const float* __restrict__ alpha1, const float* __restrict__ omega1,
           const float* __restrict__ g1, const float* __restrict__ b1,
           const float* __restrict__ cores2, const float* __restrict__ label2,
           const float* __restrict__ alpha2, const float* __restrict__ omega2,
           const float* __restrict__ g2, const float* __restrict__ b2,
           const float* __restrict__ cores3, const float* __restrict__ label3,
           const float* __restrict__ alpha3, const float* __restrict__ omega3,
           const float* __restrict__ g3, const float* __restrict__ b3,
           const float* __restrict__ coresF, const float* __restrict__ labelF,
           const float* __restrict__ alphaF, const float* __restrict__ omegaF,
           float* __restrict__ yn1, float* __restrict__ yn2,
           float* __restrict__ yn3, float* __restrict__ out) {
  __shared__ __align__(16) char smem[sizeof(Smem)];
  Smem&   sm = *reinterpret_cast<Smem*>(smem);
  F4Smem& sf = *reinterpret_cast<F4Smem*>(smem);
  const int bid = blockIdx.x, t = threadIdx.x;
  constexpr unsigned NB = 256;

  // one-time zero of the FULL CS block (k'-columns i>=20 + pad are never written
  // by the build, but B-frag reads sweep them; 0 * A(=0) stays 0, never NaN)
  {
    int* cz = (int*)&sm.CS[0][0][0];
    for (int i = t; i < (int)(sizeof(sm.CS) / 4); i += 256) cz[i] = 0;
  }

  auto computeLw = [&](const float* label, const float* omega) {
    for (int e = t; e < 400; e += 256) {
      int o = e / 20, j = e % 20;
      float a = 0.f;
#pragma unroll
      for (int k = 0; k < 20; ++k) a = fmaf(label[o * 400 + j * 20 + k], omega[k], a);
      sm.Lw[e] = a;
    }
  };

  // PH1: stage 1, 1024 patches, 4 sequential per block
  computeLw(label1, omega1);
  for (int pp = 0; pp < 4; ++pp)
    mps_stage<1>(sm, bid * 4 + pp, t, x, nullptr, cores1, alpha1, g1, b1, yn1);
  gridbar(NB);

  // PH2: stage 2, 256 patches
  computeLw(label2, omega2);
  mps_stage<2>(sm, bid, t, nullptr, yn1, cores2, alpha2, g2, b2, yn2);
  gridbar(NB);

  // PH3: stage 3, 64 patches
  if (bid < 64) {
    computeLw(label3, omega3);
    mps_stage<3>(sm, bid, t, nullptr, yn2, cores3, alpha3, g3, b3, yn3);
  }
  gridbar(NB);

  // PH4+5: final MPS, blocks 0..63 (one batch row each)
  if (bid < 64)
    final_mps(sf, bid, t, yn3, coresF, alphaF, labelF, omegaF, out);
}

extern "C" void kernel_launch(void* const* d_in, const int* in_sizes, int n_in,
                              void* d_out, int out_size, void* d_ws, size_t ws_size,
                              hipStream_t stream) {
  const float* x      = (const float*)d_in[0];
  const float* cores1 = (const float*)d_in[1];
  const float* label1 = (const float*)d_in[2];
  const float* alpha1 = (const float*)d_in[3];
  const float* omega1 = (const float*)d_in[4];
  const float* g1     = (const float*)d_in[5];
  const float* b1     = (const float*)d_in[6];
  const float* cores2 = (const float*)d_in[7];
  const float* label2 = (const float*)d_in[8];
  const float* alpha2 = (const float*)d_in[9];
  const float* omega2 = (const float*)d_in[10];
  const float* g2     = (const float*)d_in[11];
  const float* b2     = (const float*)d_in[12];
  const float* cores3 = (const float*)d_in[13];
  const float* label3 = (const float*)d_in[14];
  const float* alpha3 = (const float*)d_in[15];
  const float* omega3 = (const float*)d_in[16];
  const float* g3     = (const float*)d_in[17];
  const float* b3     = (const float*)d_in[18];
  const float* coresF = (const float*)d_in[19];
  const float* labelF = (const float*)d_in[20];
  const float* alphaF = (const float*)d_in[21];
  const float* omegaF = (const float*)d_in[22];

  float* ws  = (float*)d_ws;
  float* yn1 = ws;               // 1,310,720 f
  float* yn2 = yn1 + 1310720;    //   327,680 f
  float* yn3 = yn2 + 327680;     //    81,920 f
  float* out = (float*)d_out;

  k_all<<<256, 256, 0, stream>>>(
      x, cores1, label1, alpha1, omega1, g1, b1,
      cores2, label2, alpha2, omega2, g2, b2,
      cores3, label3, alpha3, omega3, g3, b3,
      coresF, labelF, alphaF, omegaF,
      yn1, yn2, yn3, out);
}

// Round 5
// 282.356 us; speedup vs baseline: 1.7867x; 1.7867x over previous
//
#include <hip/hip_runtime.h>
#include <hip/hip_bf16.h>

typedef __attribute__((ext_vector_type(4))) float f32x4;
typedef __attribute__((ext_vector_type(8))) short s16x8;

static __device__ __forceinline__ short f2bf(float x) {
  __hip_bfloat16 h = __float2bfloat16(x);
  return *reinterpret_cast<short*>(&h);
}

// ---------------- MFMA MPS stages 1..3 with fused BatchNorm + inline Lw ----------------
// PROVEN 255us baseline body — byte-identical. Block = patch p, 256 thr = 4 waves.
// Wave q owns batch rows [16q,16q+16). v (fp32, canonical in LDS) updated per site
// via bf16 MFMA correction; one barrier per site; prefetch distance 3 via two
// ping-pong register sets (manually unrolled x2 site loop).
template<int STAGE>
__global__ __launch_bounds__(256)
void k_mps(const float* __restrict__ xsrc, const float* __restrict__ ysrc,
           const float* __restrict__ cores, const float* __restrict__ alpha,
           const float* __restrict__ label, const float* __restrict__ omega,
           const float* __restrict__ gam, const float* __restrict__ bet,
           float* __restrict__ yout) {
  constexpr int S = (STAGE == 1) ? 3 : 20;
  __shared__ __align__(16) float u4[S][64][4];      // [site][b][g]
  __shared__ __align__(16) short Cl[2][32][168];    // [buf][n-row][k'], pad 168
  __shared__ __align__(16) float vls[64][36];       // [b][i], cols 20..35 zero
  __shared__ float Lw_l[400];
  __shared__ float redA[4], redB[4], stats[2];

  const int p = blockIdx.x, t = threadIdx.x;
  const int b = t & 63, q = t >> 6;
  const int m = b & 15, quad = b >> 4;
  const int bl = q * 16 + m;

  const bool two = (t < 144);                        // 400 = 256 + 144
  const float* cbase = cores + (size_t)p * S * 3200;

  // ---- issue site-0 raw core loads (in flight during all init) ----
  float p0A[8], p0B[8], p1A[8], p1B[8];
#pragma unroll
  for (int g = 0; g < 8; ++g) p0A[g] = cbase[g * 400 + t];
  if (two) {
#pragma unroll
    for (int g = 0; g < 8; ++g) p0B[g] = cbase[g * 400 + 256 + t];
  }

  // ---- Lw[o][j] = sum_k label[o][j][k]*omega[k] ----
  for (int e = t; e < 400; e += 256) {
    int o = e / 20, j = e % 20;
    float a = 0.f;
#pragma unroll
    for (int k = 0; k < 20; ++k) a = fmaf(label[o * 400 + j * 20 + k], omega[k], a);
    Lw_l[e] = a;
  }

  // ---- zero FULL C' (both buffers); init v = alpha (cols >=20 zero) ----
  {
    int* cz = (int*)&Cl[0][0][0];                    // 2*32*168 shorts = 5376 ints
    for (int i = t; i < 5376; i += 256) cz[i] = 0;
    for (int i = t; i < 64 * 36; i += 256) {
      int col = i % 36;
      vls[i / 36][col] = (col < 20) ? alpha[col] : 0.f;
    }
  }

  // ---- gather u (faithful raw-reshape unfold permutation); u4[k][b][g=q] ----
  for (int k = 0; k < S; ++k) {
    float val;
    if (STAGE == 1) {
      int L = q * 3072 + p * 3 + k;           // [4,1024,3] flat
      int c = L >> 12, r = L & 4095;          // dims [3,32,32,2,2]
      int hh = 2 * (r >> 7) + ((r >> 1) & 1);
      int ww = 2 * ((r >> 2) & 31) + (r & 1);
      val = xsrc[(b * 3 + c) * 4096 + hh * 64 + ww];
    } else if (STAGE == 2) {
      int L = q * 5120 + p * 20 + k;          // [4,256,20] flat
      int c = L >> 10, r = L & 1023;          // dims [20,16,16,2,2]
      int f = c * 1024 + (2 * (r >> 6) + ((r >> 1) & 1)) * 32
                        + (2 * ((r >> 2) & 15) + (r & 1));
      val = ysrc[f * 64 + b];                 // b innermost -> coalesced
    } else {
      int L = q * 1280 + p * 20 + k;          // [4,64,20] flat
      int c = L >> 8, r = L & 255;            // dims [20,8,8,2,2]
      int f = c * 256 + (2 * (r >> 5) + ((r >> 1) & 1)) * 16
                       + (2 * ((r >> 2) & 7) + (r & 1));
      val = ysrc[f * 64 + b];
    }
    u4[k][b][q] = val;
  }

  // C'-entry writer: entry e=(i*20+j) from raw feature regs r[0..8)
  auto writeC = [&](int buf, int e, const float* r) {
    int i = e / 20, j = e % 20;
    Cl[buf][j][      i] = f2bf(r[0] - r[4]);
    Cl[buf][j][ 32 + i] = f2bf(r[1] - r[5]);
    Cl[buf][j][ 64 + i] = f2bf(r[2] - r[6]);
    Cl[buf][j][ 96 + i] = f2bf(r[3] - r[7]);
    float cs = r[4] + r[5] + r[6] + r[7];
    if (i == j) cs -= 1.f;
    Cl[buf][j][128 + i] = f2bf(cs);
  };
  auto loadSite = [&](int s, float (&rA)[8], float (&rB)[8]) {
    const float* cs = cbase + (size_t)s * 3200;
#pragma unroll
    for (int g = 0; g < 8; ++g) rA[g] = cs[g * 400 + t];
    if (two) {
#pragma unroll
      for (int g = 0; g < 8; ++g) rB[g] = cs[g * 400 + 256 + t];
    }
  };

  // build C'[0] from site-0 regs; then fill the pipeline: s1 -> P0, s2 -> P1
  writeC(0, t, p0A);
  if (two) writeC(0, t + 256, p0B);
  if (S > 1) loadSite(1, p0A, p0B);
  if (S > 2) loadSite(2, p1A, p1B);
  __syncthreads();

  // ---- one site step; cur/regset passed statically (no dynamic reg indexing) ----
  auto site_step = [&](int s, int cur, float (&rA)[8], float (&rB)[8]) {
    const float4 uu = *(const float4*)&u4[s][bl][0];
    const float4 va = *(const float4*)&vls[bl][quad * 8];
    const float4 vb = *(const float4*)&vls[bl][quad * 8 + 4];
    const float vv[8] = {va.x, va.y, va.z, va.w, vb.x, vb.y, vb.z, vb.w};
    const float um[5] = {uu.x, uu.y, uu.z, uu.w, 1.f};

    f32x4 acc0 = {0.f, 0.f, 0.f, 0.f};
    f32x4 acc1 = {0.f, 0.f, 0.f, 0.f};
#pragma unroll
    for (int kt = 0; kt < 5; ++kt) {
      s16x8 aF;
#pragma unroll
      for (int j2 = 0; j2 < 8; ++j2) aF[j2] = f2bf(vv[j2] * um[kt]);
      const s16x8 bF0 = *(const s16x8*)&Cl[cur][m][kt * 32 + quad * 8];
      const s16x8 bF1 = *(const s16x8*)&Cl[cur][m + 16][kt * 32 + quad * 8];
      acc0 = __builtin_amdgcn_mfma_f32_16x16x32_bf16(aF, bF0, acc0, 0, 0, 0);
      acc1 = __builtin_amdgcn_mfma_f32_16x16x32_bf16(aF, bF1, acc1, 0, 0, 0);
    }

    // stage next site's C' (regs loaded 2 sites ago); refill this regset for s+3
    if (s + 1 < S) {
      writeC(cur ^ 1, t, rA);
      if (two) writeC(cur ^ 1, t + 256, rB);
      if (s + 3 < S) loadSite(s + 3, rA, rB);
    }

    // v += dv  (intra-wave: each (b,j) owned by exactly one lane of wave q)
#pragma unroll
    for (int r = 0; r < 4; ++r) vls[q * 16 + quad * 4 + r][m] += acc0[r];
    if (m < 4) {
#pragma unroll
      for (int r = 0; r < 4; ++r) vls[q * 16 + quad * 4 + r][m + 16] += acc1[r];
    }
    __syncthreads();   // the only per-site barrier
  };

  for (int s = 0; s < S; s += 2) {
    site_step(s, 0, p0A, p0B);
    if (s + 1 < S) site_step(s + 1, 1, p1A, p1B);
  }

  // ---- epilogue: Lw projection + fused BatchNorm (stats over 64b x 20o) ----
  float vf[20];
  {
    const float4 v0 = *(const float4*)&vls[b][0];
    const float4 v1 = *(const float4*)&vls[b][4];
    const float4 v2 = *(const float4*)&vls[b][8];
    const float4 v3 = *(const float4*)&vls[b][12];
    const float4 v4 = *(const float4*)&vls[b][16];
    vf[0]=v0.x; vf[1]=v0.y; vf[2]=v0.z; vf[3]=v0.w;
    vf[4]=v1.x; vf[5]=v1.y; vf[6]=v1.z; vf[7]=v1.w;
    vf[8]=v2.x; vf[9]=v2.y; vf[10]=v2.z; vf[11]=v2.w;
    vf[12]=v3.x; vf[13]=v3.y; vf[14]=v3.z; vf[15]=v3.w;
    vf[16]=v4.x; vf[17]=v4.y; vf[18]=v4.z; vf[19]=v4.w;
  }
  float yo[5];
  float s1 = 0.f, s2 = 0.f;
#pragma unroll
  for (int jj = 0; jj < 5; ++jj) {
    int o = q * 5 + jj;
    float a = 0.f;
#pragma unroll
    for (int j = 0; j < 20; ++j) a = fmaf(vf[j], Lw_l[o * 20 + j], a);
    yo[jj] = a; s1 += a; s2 += a * a;
  }
#pragma unroll
  for (int off = 32; off > 0; off >>= 1) {
    s1 += __shfl_down(s1, off); s2 += __shfl_down(s2, off);
  }
  if (b == 0) { redA[q] = s1; redB[q] = s2; }
  __syncthreads();
  if (t == 0) {
    float S1 = redA[0] + redA[1] + redA[2] + redA[3];
    float S2 = redB[0] + redB[1] + redB[2] + redB[3];
    float mu = S1 * (1.f / 1280.f);
    float var = S2 * (1.f / 1280.f) - mu * mu;
    if (var < 0.f) var = 0.f;
    stats[0] = mu; stats[1] = var;
  }
  __syncthreads();
  float mu = stats[0], var = stats[1];
  float scale = gam[p] / sqrtf(var + 1e-5f);
  float shift = bet[p] - mu * scale;
#pragma unroll
  for (int jj = 0; jj < 5; ++jj) {
    int o = q * 5 + jj;
    yout[(p * 20 + o) * 64 + b] = fmaf(yo[jj], scale, shift);   // coalesced over b
  }
}

// ---------------- Final MPS, restructured ----------------
// OLD k_f1 read coresF 64x redundantly (512 blocks x 0.5 MB = 268 MB of L2/L3
// traffic). NEW: materialize all 64 site transfer matrices ONCE (coresF read 4x
// = 16 MB; Mmat write 6.5 MB), then one sequential 64-matrix chain per batch row
// — which is EXACTLY the reference lax.scan association ((M0*M1)*M2)...*M63.

// k_mbuild: block = (site s = bid>>2, batch quarter bq = bid&3).
// M[s][b][e] = sum_g y[b,g,s]*(lo-hi) + sum_g hi   (same per-entry math as k_f1)
__global__ __launch_bounds__(256)
void k_mbuild(const float* __restrict__ yn3, const float* __restrict__ coresF,
              float* __restrict__ Mmat) {
  __shared__ float ybn[64][20];
  const int s = blockIdx.x >> 2, bq = blockIdx.x & 3;
  const int t = threadIdx.x;
  // stage y rows of this site: yn3 flat [site*20+g][b] -> ybn[b][g]
  for (int i = t; i < 1280; i += 256) ybn[i & 63][i >> 6] = yn3[(size_t)s * 1280 + i];
  __syncthreads();
  const float* cfp = coresF + (size_t)s * 16000;    // [40][400]
  for (int e = t; e < 400; e += 256) {
    float dlt[20]; float hsum = 0.f;
#pragma unroll
    for (int g = 0; g < 20; ++g) {
      float lo = cfp[g * 400 + e], hi = cfp[(g + 20) * 400 + e];
      dlt[g] = lo - hi; hsum += hi;
    }
    for (int bb = bq * 16; bb < bq * 16 + 16; ++bb) {
      const float4* yb = (const float4*)ybn[bb];    // uniform addr -> LDS broadcast
      float yy[20];
      *(float4*)&yy[0]  = yb[0]; *(float4*)&yy[4]  = yb[1];
      *(float4*)&yy[8]  = yb[2]; *(float4*)&yy[12] = yb[3];
      *(float4*)&yy[16] = yb[4];
      float a = hsum;
#pragma unroll
      for (int g = 0; g < 20; ++g) a = fmaf(yy[g], dlt[g], a);
      Mmat[((size_t)s * 64 + bb) * 400 + e] = a;    // lanes contiguous in e
    }
  }
}

// k_chain: block = batch row b. P = M[0][b]; P = P*M[s] for s=1..63 (double-
// buffered global->reg->LDS prefetch), then alpha/label/omega projection.
__global__ __launch_bounds__(256)
void k_chain(const float* __restrict__ Mmat, const float* __restrict__ alphaF,
             const float* __restrict__ labelF, const float* __restrict__ omegaF,
             float* __restrict__ out) {
  const int b = blockIdx.x, t = threadIdx.x;
  __shared__ float Pb[2][400];
  __shared__ float Mb[2][400];
  __shared__ float LwF[200];
  __shared__ float va[20];

  if (t < 200) {
    int o = t / 20, j = t % 20;
    float a = 0.f;
#pragma unroll
    for (int k = 0; k < 20; ++k) a = fmaf(labelF[o * 400 + j * 20 + k], omegaF[k], a);
    LwF[t] = a;
  }
  // P0 = M[0][b]; prefetch M[1] into regs
  for (int e = t; e < 400; e += 256) Pb[0][e] = Mmat[(size_t)b * 400 + e];
  float r0 = Mmat[(size_t)(64 + b) * 400 + t];
  float r1 = (t < 144) ? Mmat[(size_t)(64 + b) * 400 + 256 + t] : 0.f;
  __syncthreads();

  int cur = 0;
  for (int s = 1; s < 64; ++s) {
    // publish prefetched M[s]
    Mb[s & 1][t] = r0;
    if (t < 144) Mb[s & 1][256 + t] = r1;
    __syncthreads();
    // issue M[s+1] loads (latency hides under the matmul below)
    if (s + 1 < 64) {
      r0 = Mmat[(size_t)((s + 1) * 64 + b) * 400 + t];
      if (t < 144) r1 = Mmat[(size_t)((s + 1) * 64 + b) * 400 + 256 + t];
    }
    // P <- P * M[s]
    for (int e = t; e < 400; e += 256) {
      int i = e / 20, j = e - (e / 20) * 20;
      float a = 0.f;
#pragma unroll
      for (int k = 0; k < 20; ++k)
        a = fmaf(Pb[cur][i * 20 + k], Mb[s & 1][k * 20 + j], a);
      Pb[cur ^ 1][e] = a;
    }
    cur ^= 1;
    __syncthreads();
  }
  if (t < 20) {
    float a = 0.f;
#pragma unroll
    for (int i = 0; i < 20; ++i) a = fmaf(alphaF[i], Pb[cur][i * 20 + t], a);
    va[t] = a;
  }
  __syncthreads();
  if (t < 10) {
    float a = 0.f;
#pragma unroll
    for (int j = 0; j < 20; ++j) a = fmaf(va[j], LwF[t * 20 + j], a);
    out[b * 10 + t] = a;
  }
}

extern "C" void kernel_launch(void* const* d_in, const int* in_sizes, int n_in,
                              void* d_out, int out_size, void* d_ws, size_t ws_size,
                              hipStream_t stream) {
  const float* x      = (const float*)d_in[0];
  const float* cores1 = (const float*)d_in[1];
  const float* label1 = (const float*)d_in[2];
  const float* alpha1 = (const float*)d_in[3];
  const float* omega1 = (const float*)d_in[4];
  const float* g1     = (const float*)d_in[5];
  const float* b1     = (const float*)d_in[6];
  const float* cores2 = (const float*)d_in[7];
  const float* label2 = (const float*)d_in[8];
  const float* alpha2 = (const float*)d_in[9];
  const float* omega2 = (const float*)d_in[10];
  const float* g2     = (const float*)d_in[11];
  const float* b2     = (const float*)d_in[12];
  const float* cores3 = (const float*)d_in[13];
  const float* label3 = (const float*)d_in[14];
  const float* alpha3 = (const float*)d_in[15];
  const float* omega3 = (const float*)d_in[16];
  const float* g3     = (const float*)d_in[17];
  const float* b3     = (const float*)d_in[18];
  const float* coresF = (const float*)d_in[19];
  const float* labelF = (const float*)d_in[20];
  const float* alphaF = (const float*)d_in[21];
  const float* omegaF = (const float*)d_in[22];

  float* ws   = (float*)d_ws;
  float* yn1  = ws;               // 1,310,720 f
  float* yn2  = yn1 + 1310720;    //   327,680 f
  float* yn3  = yn2 + 327680;     //    81,920 f
  float* Mmat = yn3 + 81920;      // 1,638,400 f (64 sites x 64 b x 400)
  float* out  = (float*)d_out;

  k_mps<1><<<1024, 256, 0, stream>>>(x, nullptr, cores1, alpha1, label1, omega1, g1, b1, yn1);
  k_mps<2><<<256, 256, 0, stream>>>(nullptr, yn1, cores2, alpha2, label2, omega2, g2, b2, yn2);
  k_mps<3><<<64, 256, 0, stream>>>(nullptr, yn2, cores3, alpha3, label3, omega3, g3, b3, yn3);
  k_mbuild<<<256, 256, 0, stream>>>(yn3, coresF, Mmat);
  k_chain<<<64, 256, 0, stream>>>(Mmat, alphaF, labelF, omegaF, out);
}

// Round 6
// 254.167 us; speedup vs baseline: 1.9848x; 1.1109x over previous
//
#include <hip/hip_runtime.h>
#include <hip/hip_bf16.h>

typedef __attribute__((ext_vector_type(4))) float f32x4;
typedef __attribute__((ext_vector_type(8))) short s16x8;

static __device__ __forceinline__ short f2bf(float x) {
  __hip_bfloat16 h = __float2bfloat16(x);
  return *reinterpret_cast<short*>(&h);
}

// Intra-wave LDS fence: wait own wave's DS ops; sched_barrier stops hoisting.
static __device__ __forceinline__ void wave_lgkm0() {
  asm volatile("s_waitcnt lgkmcnt(0)" ::: "memory");
  __builtin_amdgcn_sched_barrier(0);
}

// ---------------- MFMA MPS stages 1..3 with fused BatchNorm + inline Lw ----------------
// Proven 255us baseline structure; ONE change: v persists in registers as the MFMA
// C-operand (acc init = vreg, not 0), so the per-site LDS "+=" RMW becomes a pure
// D->A relayout write. Staging pipeline (prefetch distance 3, one barrier/site)
// is byte-identical to the baseline.
template<int STAGE>
__global__ __launch_bounds__(256)
void k_mps(const float* __restrict__ xsrc, const float* __restrict__ ysrc,
           const float* __restrict__ cores, const float* __restrict__ alpha,
           const float* __restrict__ label, const float* __restrict__ omega,
           const float* __restrict__ gam, const float* __restrict__ bet,
           float* __restrict__ yout) {
  constexpr int S = (STAGE == 1) ? 3 : 20;
  __shared__ __align__(16) float u4[S][64][4];      // [site][b][g]
  __shared__ __align__(16) short Cl[2][32][168];    // [buf][n-row][k'], pad 168
  __shared__ __align__(16) float vls[64][36];       // [b][i], cols 20..35 zero
  __shared__ float Lw_l[400];
  __shared__ float redA[4], redB[4], stats[2];

  const int p = blockIdx.x, t = threadIdx.x;
  const int b = t & 63, q = t >> 6;
  const int m = b & 15, quad = b >> 4;
  const int bl = q * 16 + m;

  const bool two = (t < 144);                        // 400 = 256 + 144
  const float* cbase = cores + (size_t)p * S * 3200;

  // ---- issue site-0 raw core loads (in flight during all init) ----
  float p0A[8], p0B[8], p1A[8], p1B[8];
#pragma unroll
  for (int g = 0; g < 8; ++g) p0A[g] = cbase[g * 400 + t];
  if (two) {
#pragma unroll
    for (int g = 0; g < 8; ++g) p0B[g] = cbase[g * 400 + 256 + t];
  }

  // ---- Lw[o][j] = sum_k label[o][j][k]*omega[k] ----
  for (int e = t; e < 400; e += 256) {
    int o = e / 20, j = e % 20;
    float a = 0.f;
#pragma unroll
    for (int k = 0; k < 20; ++k) a = fmaf(label[o * 400 + j * 20 + k], omega[k], a);
    Lw_l[e] = a;
  }

  // ---- zero FULL C' (both buffers); init v = alpha (cols >=20 zero) ----
  {
    int* cz = (int*)&Cl[0][0][0];                    // 2*32*168 shorts = 5376 ints
    for (int i = t; i < 5376; i += 256) cz[i] = 0;
    for (int i = t; i < 64 * 36; i += 256) {
      int col = i % 36;
      vls[i / 36][col] = (col < 20) ? alpha[col] : 0.f;
    }
  }

  // ---- v in registers, MFMA D-layout: lane(quad,m), acc0[r] = v[row q*16+quad*4+r][col m],
  //      acc1[r] = same row, col m+16 (valid only m<4; else stays 0: zero B-rows keep it 0) ----
  float vr0[4], vr1[4];
  {
    float a0 = alpha[m];
    float a1 = (m < 4) ? alpha[m + 16] : 0.f;
#pragma unroll
    for (int r = 0; r < 4; ++r) { vr0[r] = a0; vr1[r] = a1; }
  }

  // ---- gather u (faithful raw-reshape unfold permutation); u4[k][b][g=q] ----
  for (int k = 0; k < S; ++k) {
    float val;
    if (STAGE == 1) {
      int L = q * 3072 + p * 3 + k;           // [4,1024,3] flat
      int c = L >> 12, r = L & 4095;          // dims [3,32,32,2,2]
      int hh = 2 * (r >> 7) + ((r >> 1) & 1);
      int ww = 2 * ((r >> 2) & 31) + (r & 1);
      val = xsrc[(b * 3 + c) * 4096 + hh * 64 + ww];
    } else if (STAGE == 2) {
      int L = q * 5120 + p * 20 + k;          // [4,256,20] flat
      int c = L >> 10, r = L & 1023;          // dims [20,16,16,2,2]
      int f = c * 1024 + (2 * (r >> 6) + ((r >> 1) & 1)) * 32
                        + (2 * ((r >> 2) & 15) + (r & 1));
      val = ysrc[f * 64 + b];                 // b innermost -> coalesced
    } else {
      int L = q * 1280 + p * 20 + k;          // [4,64,20] flat
      int c = L >> 8, r = L & 255;            // dims [20,8,8,2,2]
      int f = c * 256 + (2 * (r >> 5) + ((r >> 1) & 1)) * 16
                       + (2 * ((r >> 2) & 7) + (r & 1));
      val = ysrc[f * 64 + b];
    }
    u4[k][b][q] = val;
  }

  // C'-entry writer: entry e=(i*20+j) from raw feature regs r[0..8)
  auto writeC = [&](int buf, int e, const float* r) {
    int i = e / 20, j = e % 20;
    Cl[buf][j][      i] = f2bf(r[0] - r[4]);
    Cl[buf][j][ 32 + i] = f2bf(r[1] - r[5]);
    Cl[buf][j][ 64 + i] = f2bf(r[2] - r[6]);
    Cl[buf][j][ 96 + i] = f2bf(r[3] - r[7]);
    float cs = r[4] + r[5] + r[6] + r[7];
    if (i == j) cs -= 1.f;
    Cl[buf][j][128 + i] = f2bf(cs);
  };
  auto loadSite = [&](int s, float (&rA)[8], float (&rB)[8]) {
    const float* cs = cbase + (size_t)s * 3200;
#pragma unroll
    for (int g = 0; g < 8; ++g) rA[g] = cs[g * 400 + t];
    if (two) {
#pragma unroll
      for (int g = 0; g < 8; ++g) rB[g] = cs[g * 400 + 256 + t];
    }
  };

  // build C'[0] from site-0 regs; then fill the pipeline: s1 -> P0, s2 -> P1
  writeC(0, t, p0A);
  if (two) writeC(0, t + 256, p0B);
  if (S > 1) loadSite(1, p0A, p0B);
  if (S > 2) loadSite(2, p1A, p1B);
  __syncthreads();

  // ---- one site step; cur/regset passed statically (no dynamic reg indexing) ----
  auto site_step = [&](int s, int cur, float (&rA)[8], float (&rB)[8]) {
    const float4 uu = *(const float4*)&u4[s][bl][0];
    const float4 va = *(const float4*)&vls[bl][quad * 8];
    const float4 vb = *(const float4*)&vls[bl][quad * 8 + 4];
    const float vv[8] = {va.x, va.y, va.z, va.w, vb.x, vb.y, vb.z, vb.w};
    const float um[5] = {uu.x, uu.y, uu.z, uu.w, 1.f};

    f32x4 acc0, acc1;
#pragma unroll
    for (int r = 0; r < 4; ++r) { acc0[r] = vr0[r]; acc1[r] = vr1[r]; }
#pragma unroll
    for (int kt = 0; kt < 5; ++kt) {
      s16x8 aF;
#pragma unroll
      for (int j2 = 0; j2 < 8; ++j2) aF[j2] = f2bf(vv[j2] * um[kt]);
      const s16x8 bF0 = *(const s16x8*)&Cl[cur][m][kt * 32 + quad * 8];
      const s16x8 bF1 = *(const s16x8*)&Cl[cur][m + 16][kt * 32 + quad * 8];
      acc0 = __builtin_amdgcn_mfma_f32_16x16x32_bf16(aF, bF0, acc0, 0, 0, 0);
      acc1 = __builtin_amdgcn_mfma_f32_16x16x32_bf16(aF, bF1, acc1, 0, 0, 0);
    }

    // stage next site's C' (regs loaded 2 sites ago); refill this regset for s+3
    if (s + 1 < S) {
      writeC(cur ^ 1, t, rA);
      if (two) writeC(cur ^ 1, t + 256, rB);
      if (s + 3 < S) loadSite(s + 3, rA, rB);
    }

    // v now lives in acc; publish D->A relayout for next site's A-read
#pragma unroll
    for (int r = 0; r < 4; ++r) { vr0[r] = acc0[r]; vr1[r] = acc1[r]; }
#pragma unroll
    for (int r = 0; r < 4; ++r) vls[q * 16 + quad * 4 + r][m] = acc0[r];
    if (m < 4) {
#pragma unroll
      for (int r = 0; r < 4; ++r) vls[q * 16 + quad * 4 + r][m + 16] = acc1[r];
    }
    __syncthreads();   // the only per-site barrier
  };

  for (int s = 0; s < S; s += 2) {
    site_step(s, 0, p0A, p0B);
    if (s + 1 < S) site_step(s + 1, 1, p1A, p1B);
  }

  // ---- epilogue: Lw projection + fused BatchNorm (stats over 64b x 20o) ----
  float vf[20];
  {
    const float4 v0 = *(const float4*)&vls[b][0];
    const float4 v1 = *(const float4*)&vls[b][4];
    const float4 v2 = *(const float4*)&vls[b][8];
    const float4 v3 = *(const float4*)&vls[b][12];
    const float4 v4 = *(const float4*)&vls[b][16];
    vf[0]=v0.x; vf[1]=v0.y; vf[2]=v0.z; vf[3]=v0.w;
    vf[4]=v1.x; vf[5]=v1.y; vf[6]=v1.z; vf[7]=v1.w;
    vf[8]=v2.x; vf[9]=v2.y; vf[10]=v2.z; vf[11]=v2.w;
    vf[12]=v3.x; vf[13]=v3.y; vf[14]=v3.z; vf[15]=v3.w;
    vf[16]=v4.x; vf[17]=v4.y; vf[18]=v4.z; vf[19]=v4.w;
  }
  float yo[5];
  float s1 = 0.f, s2 = 0.f;
#pragma unroll
  for (int jj = 0; jj < 5; ++jj) {
    int o = q * 5 + jj;
    float a = 0.f;
#pragma unroll
    for (int j = 0; j < 20; ++j) a = fmaf(vf[j], Lw_l[o * 20 + j], a);
    yo[jj] = a; s1 += a; s2 += a * a;
  }
#pragma unroll
  for (int off = 32; off > 0; off >>= 1) {
    s1 += __shfl_down(s1, off); s2 += __shfl_down(s2, off);
  }
  if (b == 0) { redA[q] = s1; redB[q] = s2; }
  __syncthreads();
  if (t == 0) {
    float S1 = redA[0] + redA[1] + redA[2] + redA[3];
    float S2 = redB[0] + redB[1] + redB[2] + redB[3];
    float mu = S1 * (1.f / 1280.f);
    float var = S2 * (1.f / 1280.f) - mu * mu;
    if (var < 0.f) var = 0.f;
    stats[0] = mu; stats[1] = var;
  }
  __syncthreads();
  float mu = stats[0], var = stats[1];
  float scale = gam[p] / sqrtf(var + 1e-5f);
  float shift = bet[p] - mu * scale;
#pragma unroll
  for (int jj = 0; jj < 5; ++jj) {
    int o = q * 5 + jj;
    yout[(p * 20 + o) * 64 + b] = fmaf(yo[jj], scale, shift);   // coalesced over b
  }
}

// ---------------- Final MPS ----------------
// k_mbuild (unchanged): materialize all 64 site transfer matrices once.
__global__ __launch_bounds__(256)
void k_mbuild(const float* __restrict__ yn3, const float* __restrict__ coresF,
              float* __restrict__ Mmat) {
  __shared__ float ybn[64][20];
  const int s = blockIdx.x >> 2, bq = blockIdx.x & 3;
  const int t = threadIdx.x;
  for (int i = t; i < 1280; i += 256) ybn[i & 63][i >> 6] = yn3[(size_t)s * 1280 + i];
  __syncthreads();
  const float* cfp = coresF + (size_t)s * 16000;    // [40][400]
  for (int e = t; e < 400; e += 256) {
    float dlt[20]; float hsum = 0.f;
#pragma unroll
    for (int g = 0; g < 20; ++g) {
      float lo = cfp[g * 400 + e], hi = cfp[(g + 20) * 400 + e];
      dlt[g] = lo - hi; hsum += hi;
    }
    for (int bb = bq * 16; bb < bq * 16 + 16; ++bb) {
      const float4* yb = (const float4*)ybn[bb];    // uniform addr -> LDS broadcast
      float yy[20];
      *(float4*)&yy[0]  = yb[0]; *(float4*)&yy[4]  = yb[1];
      *(float4*)&yy[8]  = yb[2]; *(float4*)&yy[12] = yb[3];
      *(float4*)&yy[16] = yb[4];
      float a = hsum;
#pragma unroll
      for (int g = 0; g < 20; ++g) a = fmaf(yy[g], dlt[g], a);
      Mmat[((size_t)s * 64 + bb) * 400 + e] = a;    // lanes contiguous in e
    }
  }
}

// k_fin: block = batch row bb, 512 thr = 8 waves. Wave w computes the left-fold
// product of its chunk's 8 sites WAVE-AUTONOMOUSLY (per-wave LDS, no block
// barriers, intra-wave lgkmcnt only). Then one block-level sequential combine of
// the 8 chunk products + projection — association identical to the proven
// k_f1(chunk-of-8 left fold) + k_f2(sequential combine).
__global__ __launch_bounds__(512)
void k_fin(const float* __restrict__ Mmat, const float* __restrict__ alphaF,
           const float* __restrict__ labelF, const float* __restrict__ omegaF,
           float* __restrict__ out) {
  const int bb = blockIdx.x, t = threadIdx.x;
  const int w = t >> 6, l = t & 63;
  __shared__ float Pw[8][2][400];    // per-wave running product (ping-pong)
  __shared__ float Mw[8][400];       // per-wave M staging (reused as combine T)
  __shared__ float chunkP[8][400];
  __shared__ float LwF[200];
  __shared__ float va[20];

  if (t < 200) {
    int o = t / 20, j = t % 20;
    float a = 0.f;
#pragma unroll
    for (int k = 0; k < 20; ++k) a = fmaf(labelF[o * 400 + j * 20 + k], omegaF[k], a);
    LwF[t] = a;
  }

  // ---- wave w: chunk c = w, sites 8w .. 8w+7 ----
  float pre[7];
  {
    const size_t b0 = ((size_t)(w * 8) * 64 + bb) * 400;
#pragma unroll
    for (int it = 0; it < 7; ++it) {
      int e = l + 64 * it;
      pre[it] = (e < 400) ? Mmat[b0 + e] : 0.f;
    }
#pragma unroll
    for (int it = 0; it < 7; ++it) {
      int e = l + 64 * it;
      if (e < 400) Pw[w][0][e] = pre[it];
    }
  }
  int cur = 0;
  for (int ls = 1; ls < 8; ++ls) {
    const size_t mb = ((size_t)(w * 8 + ls) * 64 + bb) * 400;
#pragma unroll
    for (int it = 0; it < 7; ++it) {
      int e = l + 64 * it;
      if (e < 400) pre[it] = Mmat[mb + e];
    }
#pragma unroll
    for (int it = 0; it < 7; ++it) {
      int e = l + 64 * it;
      if (e < 400) Mw[w][e] = pre[it];
    }
    wave_lgkm0();
    // P' = P * M  (col-cached: 60 active lanes; lane = ii*20 + j owns rows i = ii,ii+3,..)
    if (l < 60) {
      const int j = l % 20, ii = l / 20;
      float mc[20];
#pragma unroll
      for (int k = 0; k < 20; ++k) mc[k] = Mw[w][k * 20 + j];
      for (int i = ii; i < 20; i += 3) {
        float a = 0.f;
#pragma unroll
        for (int k = 0; k < 20; ++k) a = fmaf(Pw[w][cur][i * 20 + k], mc[k], a);
        Pw[w][cur ^ 1][i * 20 + j] = a;
      }
    }
    wave_lgkm0();
    cur ^= 1;
  }
#pragma unroll
  for (int it = 0; it < 7; ++it) {
    int e = l + 64 * it;
    if (e < 400) chunkP[w][e] = Pw[w][cur][e];
  }
  __syncthreads();

  // ---- sequential combine T = ((C0*C1)*C2)... (proven association) ----
  float* T0 = &Mw[0][0];
  float* T1 = &Mw[1][0];
  if (t < 400) T0[t] = chunkP[0][t];
  __syncthreads();
  float* Tc = T0; float* Tn = T1;
  for (int c = 1; c < 8; ++c) {
    if (t < 400) {
      int i = t / 20, j = t - (t / 20) * 20;
      float a = 0.f;
#pragma unroll
      for (int k = 0; k < 20; ++k) a = fmaf(Tc[i * 20 + k], chunkP[c][k * 20 + j], a);
      Tn[t] = a;
    }
    __syncthreads();
    float* tmp = Tc; Tc = Tn; Tn = tmp;
  }
  if (t < 20) {
    float a = 0.f;
#pragma unroll
    for (int i = 0; i < 20; ++i) a = fmaf(alphaF[i], Tc[i * 20 + t], a);
    va[t] = a;
  }
  __syncthreads();
  if (t < 10) {
    float a = 0.f;
#pragma unroll
    for (int j = 0; j < 20; ++j) a = fmaf(va[j], LwF[t * 20 + j], a);
    out[bb * 10 + t] = a;
  }
}

extern "C" void kernel_launch(void* const* d_in, const int* in_sizes, int n_in,
                              void* d_out, int out_size, void* d_ws, size_t ws_size,
                              hipStream_t stream) {
  const float* x      = (const float*)d_in[0];
  const float* cores1 = (const float*)d_in[1];
  const float* label1 = (const float*)d_in[2];
  const float* alpha1 = (const float*)d_in[3];
  const float* omega1 = (const float*)d_in[4];
  const float* g1     = (const float*)d_in[5];
  const float* b1     = (const float*)d_in[6];
  const float* cores2 = (const float*)d_in[7];
  const float* label2 = (const float*)d_in[8];
  const float* alpha2 = (const float*)d_in[9];
  const float* omega2 = (const float*)d_in[10];
  const float* g2     = (const float*)d_in[11];
  const float* b2     = (const float*)d_in[12];
  const float* cores3 = (const float*)d_in[13];
  const float* label3 = (const float*)d_in[14];
  const float* alpha3 = (const float*)d_in[15];
  const float* omega3 = (const float*)d_in[16];
  const float* g3     = (const float*)d_in[17];
  const float* b3     = (const float*)d_in[18];
  const float* coresF = (const float*)d_in[19];
  const float* labelF = (const float*)d_in[20];
  const float* alphaF = (const float*)d_in[21];
  const float* omegaF = (const float*)d_in[22];

  float* ws   = (float*)d_ws;
  float* yn1  = ws;               // 1,310,720 f
  float* yn2  = yn1 + 1310720;    //   327,680 f
  float* yn3  = yn2 + 327680;     //    81,920 f
  float* Mmat = yn3 + 81920;      // 1,638,400 f (64 sites x 64 b x 400)
  float* out  = (float*)d_out;

  k_mps<1><<<1024, 256, 0, stream>>>(x, nullptr, cores1, alpha1, label1, omega1, g1, b1, yn1);
  k_mps<2><<<256, 256, 0, stream>>>(nullptr, yn1, cores2, alpha2, label2, omega2, g2, b2, yn2);
  k_mps<3><<<64, 256, 0, stream>>>(nullptr, yn2, cores3, alpha3, label3, omega3, g3, b3, yn3);
  k_mbuild<<<256, 256, 0, stream>>>(yn3, coresF, Mmat);
  k_fin<<<64, 512, 0, stream>>>(Mmat, alphaF, labelF, omegaF, out);
}